// Round 13
// baseline (202.735 us; speedup 1.0000x reference)
//
#include <hip/hip_runtime.h>

#define Bsz 4
#define Nn 2048
#define Dd 256
#define Hh 4
#define HD 64
#define NTt 5
#define ETt 6
#define LOG2E 1.4426950408889634f
#define MSUB 24.0f
#define SCLQ 0.18033688011112042f   // 0.125 * LOG2E, folded into Q at qkv time

typedef float f32x4 __attribute__((ext_vector_type(4)));
typedef __bf16 bf16x8 __attribute__((ext_vector_type(8)));
typedef unsigned int u32x4 __attribute__((ext_vector_type(4)));
typedef unsigned short u16;
typedef unsigned char u8;
typedef unsigned int uint;

static __device__ __forceinline__ u16 f2bf(float f) {
  unsigned int u = __builtin_bit_cast(unsigned int, f);
  u = (u + 0x7fffu + ((u >> 16) & 1u)) >> 16;
  return (u16)u;
}

static __device__ __forceinline__ bf16x8 ld8(const u16* p) {
  return __builtin_bit_cast(bf16x8, *(const u32x4*)p);
}

// async global->LDS, 16B per lane; LDS dest = wave-uniform base + lane*16
static __device__ __forceinline__ void stage16(const void* g, void* l) {
  __builtin_amdgcn_global_load_lds(
      (const __attribute__((address_space(1))) uint*)g,
      (__attribute__((address_space(3))) uint*)l, 16, 0, 0);
}

#define MFMA16(a, b, c) __builtin_amdgcn_mfma_f32_16x16x32_bf16((a), (b), (c), 0, 0, 0)

// ---------------- ws layout (bytes) ----------------
#define OFF_X      0u            // f32  [8192][256]        8388608
#define OFF_XBF    8388608u      // bf16 [8192][256]        4194304
#define OFF_WQKVT  12582912u     // bf16 [768][256]         393216
#define OFF_WOT    12976128u     // bf16 [256][256]         131072
#define OFF_BQKV   13107200u     // f32  [768]              3072
#define OFF_Q      13110272u     // bf16 [B,H,N,64]         4194304
#define OFF_K      17304576u     // bf16 [B,H,N,64]         4194304
#define OFF_VT     25693184u     // bf16 [B,H,64,N]         4194304
#define OFF_CTX    29887488u     // bf16 [8192][256]        4194304
#define OFF_CODES  34081792u     // u8   [B,128,32,64,16]   16777216

// ================= pack weights (transposed, bf16) =================
__global__ void pack_kernel(const float* Wq, const float* Wk, const float* Wv,
                            const float* Wo, const float* bq, const float* bk,
                            const float* bv, u16* wqkvT, u16* woT, float* bqkv) {
  int tid = blockIdx.x * 256 + threadIdx.x;
  if (tid < 196608) {                 // WqkvT[c][k] = W_which[k][cc]
    int c = tid >> 8, k = tid & 255;
    int which = c >> 8, cc = c & 255;
    const float* W = (which == 0) ? Wq : ((which == 1) ? Wk : Wv);
    wqkvT[tid] = f2bf(W[k * 256 + cc]);
  } else if (tid < 262144) {          // WoT[c][k] = Wo[k][c]
    int t2 = tid - 196608;
    int c = t2 >> 8, k = t2 & 255;
    woT[t2] = f2bf(Wo[k * 256 + c]);
  } else if (tid < 262912) {
    int c = tid - 262144;
    int which = c >> 8, cc = c & 255;
    bqkv[c] = (which == 0) ? bq[cc] : ((which == 1) ? bk[cc] : bv[cc]);
  }
}

// ================= x = nodes + node_type_embed[nt] =================
__global__ void embed_kernel(const float* nodes, const int* node_types,
                             const float* nte, float* xf, u16* xbf) {
  int t = blockIdx.x * 256 + threadIdx.x;    // 524288 threads, 4 floats each
  int flat = t * 4;
  int bn = flat >> 8, d0 = flat & 255;
  int nt = node_types[bn];
  float4 nv = *(const float4*)(nodes + flat);
  float4 ev = *(const float4*)(nte + nt * 256 + d0);
  float4 x4;
  x4.x = nv.x + ev.x; x4.y = nv.y + ev.y; x4.z = nv.z + ev.z; x4.w = nv.w + ev.w;
  *(float4*)(xf + flat) = x4;
  ushort4 xb;
  xb.x = f2bf(x4.x); xb.y = f2bf(x4.y); xb.z = f2bf(x4.z); xb.w = f2bf(x4.w);
  *(ushort4*)(xbf + flat) = xb;
}

// ================= mask pack: code = (et + 6*tm + 12*adj)*4 ===============
// TRANSPOSED fragment order for swapped-operand QK^T:
// codes[b][qt16][kt][lane][word ks][byte j] covers
//   q = qt*16 + (lane&15), kcol = kt*64 + ks*16 + (lane>>4)*4 + j
__global__ __launch_bounds__(256) void maskpack_kernel(
    const int* node_types, const int* edge_types, const float* adjacency,
    u8* codes) {
  int t = blockIdx.x * 256 + threadIdx.x;   // 1048576
  int lane = t & 63;
  int kt = (t >> 6) & 31;
  int qt = (t >> 11) & 127;
  int b = t >> 18;
  int l15 = lane & 15, l4 = lane >> 4;
  const int* etb = edge_types + (size_t)b * Nn * Nn;
  const float* adjb = adjacency + (size_t)b * Nn * Nn;
  const int* ntb = node_types + b * Nn;
  int qrow = qt * 16 + l15;
  int ntq = ntb[qrow];
  const int* etr = etb + (size_t)qrow * Nn;
  const float* adr = adjb + (size_t)qrow * Nn;
  unsigned int wds[4];
#pragma unroll
  for (int ks = 0; ks < 4; ++ks) {
    int k0 = kt * 64 + ks * 16 + l4 * 4;
    int4 et4 = *(const int4*)(etr + k0);
    float4 a4 = *(const float4*)(adr + k0);
    int4 nt4 = *(const int4*)(ntb + k0);
    int e[4] = {et4.x, et4.y, et4.z, et4.w};
    int n[4] = {nt4.x, nt4.y, nt4.z, nt4.w};
    float a[4] = {a4.x, a4.y, a4.z, a4.w};
    unsigned int acc = 0;
#pragma unroll
    for (int j = 0; j < 4; ++j) {
      int code = e[j] + ((ntq == n[j]) ? 6 : 0) + ((a[j] != 0.0f) ? 12 : 0);
      acc |= (unsigned int)(code * 4) << (8 * j);
    }
    wds[ks] = acc;
  }
  u32x4 out = {wds[0], wds[1], wds[2], wds[3]};
  *(u32x4*)(codes + (size_t)t * 16) = out;
}

// ================= QKV GEMM: [8192,256] @ [256,768] =================
// Q pre-scaled by 0.125*LOG2E (f32, before bf16 round); V written TRANSPOSED
// directly to Vtb[B,H,64,N].
__global__ __launch_bounds__(256) void qkv_kernel(const u16* xbf, const u16* wqkvT,
                                                  const float* bqkv,
                                                  u16* Qb, u16* Kb, u16* Vtb) {
  int cb = blockIdx.x;              // 0..11
  int rb = blockIdx.y;              // 0..127
  int w = threadIdx.x >> 6, lane = threadIdx.x & 63;
  int l15 = lane & 15, l4 = lane >> 4;
  int row0 = rb * 64 + w * 16;
  int col0 = cb * 64;
  const u16* xr = xbf + (size_t)(row0 + l15) * 256;
  f32x4 acc[4];
#pragma unroll
  for (int i = 0; i < 4; ++i) acc[i] = (f32x4){0.f, 0.f, 0.f, 0.f};
#pragma unroll
  for (int kst = 0; kst < 8; ++kst) {
    int k0 = kst * 32 + l4 * 8;
    bf16x8 a = ld8(xr + k0);
#pragma unroll
    for (int cs = 0; cs < 4; ++cs) {
      int col = col0 + cs * 16 + l15;
      bf16x8 bw = ld8(wqkvT + (size_t)col * 256 + k0);
      acc[cs] = MFMA16(a, bw, acc[cs]);
    }
  }
#pragma unroll
  for (int cs = 0; cs < 4; ++cs) {
    int col = col0 + cs * 16 + l15;
    float bias = bqkv[col];
    int which = col >> 8, c = col & 255;
    int h = c >> 6, hd = c & 63;
    float scale = (which == 0) ? SCLQ : 1.0f;
#pragma unroll
    for (int j = 0; j < 4; ++j) {
      int row = row0 + l4 * 4 + j;
      int bb = row >> 11, n = row & 2047;
      u16 val = f2bf((acc[cs][j] + bias) * scale);
      if (which == 2)
        Vtb[((size_t)((bb * Hh + h) * HD + hd)) * Nn + n] = val;
      else if (which == 0)
        Qb[(size_t)(((bb * Hh + h) * Nn + n)) * HD + hd] = val;
      else
        Kb[(size_t)(((bb * Hh + h) * Nn + n)) * HD + hd] = val;
    }
  }
}

// ================= attention: single fused loop =================
// block = (b, h, 16-row q-tile): 2048 blocks x 4 waves; wave w owns k-range
// [w*512, w*512+512) = 8 kt of 64. ONE loop does QK^T+bias+exp2 (packed to
// bf16 regs p[8][8]) AND PV with unnormalized P (scale commutes). V(kt) stage
// hides under QK compute; K(kt+1) restage hides under PV — K/V each use a
// single wave-private 8KB buffer alternately. Counted vmcnt, ZERO barriers in
// the loop. Epilogue: row-sum combine, then a dependency-free attn store loop
// (pure streaming), then ctx scale + cross-wave combine.
__global__ __launch_bounds__(256) void attn_kernel(
    const u16* Qb, const u16* Kb, const u16* Vtb, const u8* codes,
    const float* ee_g, float* attn_out, u16* ctx_ws) {
  __shared__ __align__(16) char kvb[4][2][8192];   // [w][0]=K buf, [w][1]=V buf
  __shared__ __align__(16) char pls[4][2048];      // per-wave P roundtrip
  __shared__ float lsh[4][16];

  int bid0 = blockIdx.x;
  int bid = ((bid0 & 7) << 8) | (bid0 >> 3);   // XCD-chunked (2048 % 8 == 0)
  int qt = bid & 127;
  int h = (bid >> 7) & 3;
  int b = bid >> 9;
  int w = threadIdx.x >> 6, lane = threadIdx.x & 63;
  int l15 = lane & 15, l4 = lane >> 4;
  int q0 = qt * 16;
  int bh = b * Hh + h;
  int wk0 = w * 512;                 // this wave's k-range start

  // 24-entry bias LUT (log2 domain, MSUB folded in), one value per lane 0..23
  float lutv = 0.f;
  {
    int ln = lane;
    int et = ln - 6 * (ln / 6);
    int tm = (ln / 6) & 1;
    int adj = ln / 12;
    if (ln < 24)
      lutv = (ee_g[et * Hh + h] + (tm ? 0.10f : -0.05f)) * LOG2E +
             (adj ? 0.f : -1.442695041e9f) - MSUB;
  }
  int lut_i = __float_as_int(lutv);

  // Q as B-fragment (pre-scaled by SCLQ in qkv_kernel)
  const u16* Qp = Qb + (size_t)(bh * Nn + q0 + l15) * HD;
  bf16x8 bq0 = ld8(Qp + l4 * 8);
  bf16x8 bq1 = ld8(Qp + 32 + l4 * 8);

  const char* Kgw = (const char*)(Kb + (size_t)bh * Nn * HD) + (size_t)wk0 * 128;
  const char* Vg = (const char*)(Vtb + (size_t)bh * HD * Nn);
  const u32x4* cp = (const u32x4*)codes + ((size_t)(b * 128 + qt) * 32) * 64;

  // staging: 8KB tile = 64 rows x 128B; LDS[o] = G[row*stride + swz(o)&127]
  int oS[8];
  const char* KgS[8];
  const char* VgS[8];
#pragma unroll
  for (int j = 0; j < 8; ++j) {
    int o = j * 1024 + lane * 16;
    oS[j] = o;
    int row = o >> 7;
    int sz = (o ^ ((row & 7) << 4)) & 127;
    KgS[j] = Kgw + (size_t)row * 128 + sz;                 // + kt*8192
    VgS[j] = Vg + (size_t)row * (Nn * 2) + wk0 * 2 + sz;   // + kt*128
  }
  char* kbuf = (char*)kvb[w][0];
  char* vbuf = (char*)kvb[w][1];

  int sw = (l15 & 7) << 4;
  int ra = (l15 * 128 + l4 * 16) ^ sw;
  char* pwave = (char*)pls[w];
  int pwbase = l15 * 128;

  uint p[8][8];                      // bf16x2 packed exp2 values
  float accl = 0.f;
  f32x4 ctx[4];
#pragma unroll
  for (int i = 0; i < 4; ++i) ctx[i] = (f32x4){0.f, 0.f, 0.f, 0.f};

  // drain Q / ee_g loads so the FIFO count below is exact
  asm volatile("s_waitcnt vmcnt(0)" ::: "memory");
  __builtin_amdgcn_sched_barrier(0);
  u32x4 cw = cp[(size_t)(w * 8) * 64 + lane];      // codes(0)   [oldest]
#pragma unroll
  for (int j = 0; j < 8; ++j) stage16(KgS[j], kbuf + oS[j]);   // K(0)
  __builtin_amdgcn_sched_barrier(0);
  // FIFO: [cw 1, K0 8] = 9

#pragma unroll
  for (int i = 0; i < 8; ++i) {
    // issue V(i) stage (hides under QK compute)
#pragma unroll
    for (int j = 0; j < 8; ++j)
      stage16(VgS[j] + (size_t)i * 128, vbuf + oS[j]);
    u32x4 cwn = cw;
    if (i < 7) cwn = cp[(size_t)(w * 8 + i + 1) * 64 + lane];
    __builtin_amdgcn_sched_barrier(0);
    // drain cw(i)+K(i); leave V(i) (+cwn) in flight
    if (i < 7) asm volatile("s_waitcnt vmcnt(9) lgkmcnt(0)" ::: "memory");
    else       asm volatile("s_waitcnt vmcnt(8) lgkmcnt(0)" ::: "memory");
    __builtin_amdgcn_sched_barrier(0);

    // ---- QK^T + bias-Cinit + exp2 + pack ----
#pragma unroll
    for (int ks = 0; ks < 4; ++ks) {
      unsigned int cword = cw[ks];
      f32x4 acc;
#pragma unroll
      for (int j = 0; j < 4; ++j)
        acc[j] = __int_as_float(
            __builtin_amdgcn_ds_bpermute((cword >> (8 * j)) & 0xFF, lut_i));
      acc = MFMA16(ld8((const u16*)(kbuf + ra + ks * 2048)), bq0, acc);
      acc = MFMA16(ld8((const u16*)(kbuf + (ra ^ 64) + ks * 2048)), bq1, acc);
      float e0 = __builtin_amdgcn_exp2f(acc[0]);
      float e1 = __builtin_amdgcn_exp2f(acc[1]);
      float e2 = __builtin_amdgcn_exp2f(acc[2]);
      float e3 = __builtin_amdgcn_exp2f(acc[3]);
      accl += (e0 + e1) + (e2 + e3);
      asm("v_cvt_pk_bf16_f32 %0, %1, %2" : "=v"(p[i][ks * 2]) : "v"(e0), "v"(e1));
      asm("v_cvt_pk_bf16_f32 %0, %1, %2" : "=v"(p[i][ks * 2 + 1]) : "v"(e2), "v"(e3));
    }
    // kbuf ds_reads retired -> safe to restage K(i+1) (hides under PV)
    __builtin_amdgcn_sched_barrier(0);
    asm volatile("s_waitcnt lgkmcnt(0)" ::: "memory");
    __builtin_amdgcn_sched_barrier(0);
    if (i < 7) {
#pragma unroll
      for (int j = 0; j < 8; ++j)
        stage16(KgS[j] + (size_t)(i + 1) * 8192, kbuf + oS[j]);
    }
    __builtin_amdgcn_sched_barrier(0);
    // drain V(i); leave cwn + K(i+1) in flight
    if (i < 7) asm volatile("s_waitcnt vmcnt(9) lgkmcnt(0)" ::: "memory");
    else       asm volatile("s_waitcnt vmcnt(0) lgkmcnt(0)" ::: "memory");
    __builtin_amdgcn_sched_barrier(0);

    // ---- PV with unnormalized P ----
#pragma unroll
    for (int ks = 0; ks < 4; ++ks) {
      int2 wv = {(int)p[i][ks * 2], (int)p[i][ks * 2 + 1]};
      *(int2*)(pwave + pwbase + ((ks * 32 + l4 * 8) ^ sw)) = wv;
    }
#pragma unroll
    for (int half = 0; half < 2; ++half) {
      bf16x8 pa = ld8((const u16*)(pwave + pwbase + ((half * 64 + l4 * 16) ^ sw)));
#pragma unroll
      for (int d = 0; d < 4; ++d) {
        bf16x8 v = ld8((const u16*)(vbuf + d * 2048 + l15 * 128 +
                                    ((half * 64 + l4 * 16) ^ sw)));
        ctx[d] = MFMA16(pa, v, ctx[d]);
      }
    }
    cw = cwn;
  }

  // ---- row-sum combine across the 4 k-split waves ----
  accl += __shfl_xor(accl, 16);
  accl += __shfl_xor(accl, 32);
  if (lane < 16) lsh[w][lane] = accl;
  __syncthreads();
  float tot = lsh[0][l15] + lsh[1][l15] + lsh[2][l15] + lsh[3][l15];
  bool zrow = (tot == 0.0f);
  float pscale = zrow ? 0.0f : 1.0f / tot;
  float pbias = zrow ? (1.0f / 2048.0f) : 0.0f;

  // ---- attn store loop: pure streaming from registers ----
  float* attb = attn_out + (size_t)bh * Nn * Nn + (size_t)(q0 + l15) * Nn + wk0;
#pragma unroll
  for (int i = 0; i < 8; ++i) {
#pragma unroll
    for (int ks = 0; ks < 4; ++ks) {
      uint u0 = p[i][ks * 2], u1 = p[i][ks * 2 + 1];
      f32x4 o;
      o[0] = __int_as_float((int)(u0 << 16)) * pscale + pbias;
      o[1] = __int_as_float((int)(u0 & 0xFFFF0000u)) * pscale + pbias;
      o[2] = __int_as_float((int)(u1 << 16)) * pscale + pbias;
      o[3] = __int_as_float((int)(u1 & 0xFFFF0000u)) * pscale + pbias;
      __builtin_nontemporal_store(o, (f32x4*)(attb + i * 64 + ks * 16 + l4 * 4));
    }
  }

  // ---- per-row scale of partial ctx, then cross-wave combine ----
  float cscale = pscale + pbias;   // zrow: 1/2048 (ctx stays ~0; impossible case)
  float csr[4];
#pragma unroll
  for (int j = 0; j < 4; ++j)
    csr[j] = __int_as_float(
        __builtin_amdgcn_ds_bpermute((l4 * 4 + j) * 4, __float_as_int(cscale)));
#pragma unroll
  for (int d = 0; d < 4; ++d)
#pragma unroll
    for (int j = 0; j < 4; ++j) ctx[d][j] *= csr[j];

  __syncthreads();                       // all waves done with kvb as K/V
  float* creg = (float*)kvb;
  if (w > 0) {
    float* cs_ = creg + ((size_t)(w - 1) * 64 + lane) * 17;
#pragma unroll
    for (int d = 0; d < 4; ++d)
#pragma unroll
      for (int j = 0; j < 4; ++j) cs_[d * 4 + j] = ctx[d][j];
  }
  __syncthreads();
  if (w == 0) {
    float* c0 = creg + (size_t)lane * 17;
    float* c1 = creg + ((size_t)64 + lane) * 17;
    float* c2 = creg + ((size_t)128 + lane) * 17;
#pragma unroll
    for (int d = 0; d < 4; ++d) {
      int col = h * 64 + d * 16 + l15;
#pragma unroll
      for (int j = 0; j < 4; ++j) {
        float v = ctx[d][j] + c0[d * 4 + j] + c1[d * 4 + j] + c2[d * 4 + j];
        int qrow = q0 + l4 * 4 + j;
        ctx_ws[(size_t)(b * Nn + qrow) * Dd + col] = f2bf(v);
      }
    }
  }
}

// ================= out GEMM + residual + LayerNorm =================
__global__ __launch_bounds__(256) void outln_kernel(const u16* ctxb, const u16* woT,
                                                    const float* bo, const float* xf,
                                                    const float* ln_g, const float* ln_b,
                                                    float* yout) {
  __shared__ float ytile[32][257];
  __shared__ float muS[32], rvS[32];
  int bm0 = blockIdx.x * 32;
  int w = threadIdx.x >> 6, lane = threadIdx.x & 63;
  int l15 = lane & 15, l4 = lane >> 4;
  f32x4 acc[2][4];
#pragma unroll
  for (int q = 0; q < 2; ++q)
#pragma unroll
    for (int i = 0; i < 4; ++i) acc[q][i] = (f32x4){0.f, 0.f, 0.f, 0.f};
#pragma unroll
  for (int kst = 0; kst < 8; ++kst) {
    int k0 = kst * 32 + l4 * 8;
    bf16x8 a0 = ld8(ctxb + (size_t)(bm0 + l15) * 256 + k0);
    bf16x8 a1 = ld8(ctxb + (size_t)(bm0 + 16 + l15) * 256 + k0);
#pragma unroll
    for (int ds_ = 0; ds_ < 4; ++ds_) {
      bf16x8 bw = ld8(woT + (size_t)(w * 64 + ds_ * 16 + l15) * 256 + k0);
      acc[0][ds_] = MFMA16(a0, bw, acc[0][ds_]);
      acc[1][ds_] = MFMA16(a1, bw, acc[1][ds_]);
    }
  }
#pragma unroll
  for (int qs = 0; qs < 2; ++qs)
#pragma unroll
    for (int ds_ = 0; ds_ < 4; ++ds_) {
      int col = w * 64 + ds_ * 16 + l15;
      float bof = bo[col];
#pragma unroll
      for (int j = 0; j < 4; ++j) {
        int row = qs * 16 + l4 * 4 + j;
        ytile[row][col] = acc[qs][ds_][j] + bof + xf[(size_t)(bm0 + row) * 256 + col];
      }
    }
  __syncthreads();
  int row = threadIdx.x >> 3, seg = threadIdx.x & 7;
  float ps = 0.f, pq = 0.f;
#pragma unroll
  for (int c = 0; c < 32; ++c) {
    float v = ytile[row][seg * 32 + c];
    ps += v; pq += v * v;
  }
  ps += __shfl_xor(ps, 1); pq += __shfl_xor(pq, 1);
  ps += __shfl_xor(ps, 2); pq += __shfl_xor(pq, 2);
  ps += __shfl_xor(ps, 4); pq += __shfl_xor(pq, 4);
  if (seg == 0) {
    float mu = ps * (1.0f / 256.0f);
    muS[row] = mu;
    rvS[row] = rsqrtf(pq * (1.0f / 256.0f) - mu * mu + 1e-5f);
  }
  __syncthreads();
  float mu = muS[row], rv = rvS[row];
  float* yr = yout + (size_t)(bm0 + row) * 256;
#pragma unroll
  for (int c0 = 0; c0 < 32; c0 += 4) {
    int c = seg * 32 + c0;
    float4 o;
    o.x = (ytile[row][c + 0] - mu) * rv * ln_g[c + 0] + ln_b[c + 0];
    o.y = (ytile[row][c + 1] - mu) * rv * ln_g[c + 1] + ln_b[c + 1];
    o.z = (ytile[row][c + 2] - mu) * rv * ln_g[c + 2] + ln_b[c + 2];
    o.w = (ytile[row][c + 3] - mu) * rv * ln_g[c + 3] + ln_b[c + 3];
    *(float4*)(yr + c) = o;
  }
}

extern "C" void kernel_launch(void* const* d_in, const int* in_sizes, int n_in,
                              void* d_out, int out_size, void* d_ws, size_t ws_size,
                              hipStream_t stream) {
  const float* nodes = (const float*)d_in[0];
  const int* node_types = (const int*)d_in[1];
  const int* edge_types = (const int*)d_in[2];
  const float* adjacency = (const float*)d_in[3];
  const float* nte = (const float*)d_in[4];
  const float* ee = (const float*)d_in[5];
  const float* Wq = (const float*)d_in[6];
  const float* bq = (const float*)d_in[7];
  const float* Wk = (const float*)d_in[8];
  const float* bk = (const float*)d_in[9];
  const float* Wv = (const float*)d_in[10];
  const float* bv = (const float*)d_in[11];
  const float* Wo = (const float*)d_in[12];
  const float* bo = (const float*)d_in[13];
  const float* ln_g = (const float*)d_in[14];
  const float* ln_b = (const float*)d_in[15];

  float* y = (float*)d_out;
  float* attn = y + (size_t)Bsz * Nn * Dd;

  char* ws = (char*)d_ws;
  float* xf = (float*)(ws + OFF_X);
  u16* xbf = (u16*)(ws + OFF_XBF);
  u16* wqkvT = (u16*)(ws + OFF_WQKVT);
  u16* woT = (u16*)(ws + OFF_WOT);
  float* bqkv = (float*)(ws + OFF_BQKV);
  u16* Qb = (u16*)(ws + OFF_Q);
  u16* Kb = (u16*)(ws + OFF_K);
  u16* Vtb = (u16*)(ws + OFF_VT);
  u16* ctxb = (u16*)(ws + OFF_CTX);
  u8* codes = (u8*)(ws + OFF_CODES);

  pack_kernel<<<1027, 256, 0, stream>>>(Wq, Wk, Wv, Wo, bq, bk, bv, wqkvT, woT, bqkv);
  embed_kernel<<<2048, 256, 0, stream>>>(nodes, node_types, nte, xf, xbf);
  maskpack_kernel<<<4096, 256, 0, stream>>>(node_types, edge_types, adjacency, codes);
  qkv_kernel<<<dim3(12, 128), 256, 0, stream>>>(xbf, wqkvT, bqkv, Qb, Kb, Vtb);
  attn_kernel<<<2048, 256, 0, stream>>>(Qb, Kb, Vtb, codes, ee, attn, ctxb);
  outln_kernel<<<256, 256, 0, stream>>>(ctxb, woT, bo, xf, ln_g, ln_b, y);
}

// Round 14
// 184.470 us; speedup vs baseline: 1.0990x; 1.0990x over previous
//
#include <hip/hip_runtime.h>

#define Bsz 4
#define Nn 2048
#define Dd 256
#define Hh 4
#define HD 64
#define NTt 5
#define ETt 6
#define LOG2E 1.4426950408889634f
#define MSUB 24.0f
#define SCLQ 0.18033688011112042f   // 0.125 * LOG2E, folded into Q at qkv time

typedef float f32x4 __attribute__((ext_vector_type(4)));
typedef __bf16 bf16x8 __attribute__((ext_vector_type(8)));
typedef unsigned int u32x4 __attribute__((ext_vector_type(4)));
typedef unsigned short u16;
typedef unsigned char u8;
typedef unsigned int uint;

static __device__ __forceinline__ u16 f2bf(float f) {
  unsigned int u = __builtin_bit_cast(unsigned int, f);
  u = (u + 0x7fffu + ((u >> 16) & 1u)) >> 16;
  return (u16)u;
}

static __device__ __forceinline__ bf16x8 ld8(const u16* p) {
  return __builtin_bit_cast(bf16x8, *(const u32x4*)p);
}

// async global->LDS, 16B per lane; LDS dest = wave-uniform base + lane*16
static __device__ __forceinline__ void stage16(const void* g, void* l) {
  __builtin_amdgcn_global_load_lds(
      (const __attribute__((address_space(1))) uint*)g,
      (__attribute__((address_space(3))) uint*)l, 16, 0, 0);
}

#define MFMA16(a, b, c) __builtin_amdgcn_mfma_f32_16x16x32_bf16((a), (b), (c), 0, 0, 0)

// ---------------- ws layout (bytes) ----------------
#define OFF_X      0u            // f32  [8192][256]        8388608
#define OFF_XBF    8388608u      // bf16 [8192][256]        4194304
#define OFF_WQKVT  12582912u     // bf16 [768][256]         393216
#define OFF_WOT    12976128u     // bf16 [256][256]         131072
#define OFF_BQKV   13107200u     // f32  [768]              3072
#define OFF_Q      13110272u     // bf16 [B,H,N,64]         4194304
#define OFF_K      17304576u     // bf16 [B,H,N,64]         4194304
#define OFF_VT     25693184u     // bf16 [B,H,64,N]         4194304
#define OFF_CTX    29887488u     // bf16 [8192][256]        4194304
#define OFF_CODES  34081792u     // u8   [B,128,32,64,16]   16777216

// ================= pack weights (transposed, bf16) =================
__global__ void pack_kernel(const float* Wq, const float* Wk, const float* Wv,
                            const float* Wo, const float* bq, const float* bk,
                            const float* bv, u16* wqkvT, u16* woT, float* bqkv) {
  int tid = blockIdx.x * 256 + threadIdx.x;
  if (tid < 196608) {                 // WqkvT[c][k] = W_which[k][cc]
    int c = tid >> 8, k = tid & 255;
    int which = c >> 8, cc = c & 255;
    const float* W = (which == 0) ? Wq : ((which == 1) ? Wk : Wv);
    wqkvT[tid] = f2bf(W[k * 256 + cc]);
  } else if (tid < 262144) {          // WoT[c][k] = Wo[k][c]
    int t2 = tid - 196608;
    int c = t2 >> 8, k = t2 & 255;
    woT[t2] = f2bf(Wo[k * 256 + c]);
  } else if (tid < 262912) {
    int c = tid - 262144;
    int which = c >> 8, cc = c & 255;
    bqkv[c] = (which == 0) ? bq[cc] : ((which == 1) ? bk[cc] : bv[cc]);
  }
}

// ================= x = nodes + node_type_embed[nt] =================
__global__ void embed_kernel(const float* nodes, const int* node_types,
                             const float* nte, float* xf, u16* xbf) {
  int t = blockIdx.x * 256 + threadIdx.x;    // 524288 threads, 4 floats each
  int flat = t * 4;
  int bn = flat >> 8, d0 = flat & 255;
  int nt = node_types[bn];
  float4 nv = *(const float4*)(nodes + flat);
  float4 ev = *(const float4*)(nte + nt * 256 + d0);
  float4 x4;
  x4.x = nv.x + ev.x; x4.y = nv.y + ev.y; x4.z = nv.z + ev.z; x4.w = nv.w + ev.w;
  *(float4*)(xf + flat) = x4;
  ushort4 xb;
  xb.x = f2bf(x4.x); xb.y = f2bf(x4.y); xb.z = f2bf(x4.z); xb.w = f2bf(x4.w);
  *(ushort4*)(xbf + flat) = xb;
}

// ================= mask pack v2: LDS-transposed, coalesced R/W ============
// block = (b, qt16): Phase A reads et/adj/nt fully coalesced (consecutive
// int4 within a row), computes word = 4 codes (k0..k0+3), stores to padded
// LDS; Phase B re-reads in fragment order and writes codes as contiguous
// dwordx4 streams. Layout (consumed by attn, unchanged):
//   codes byte = rec(b,qt)*32768 + kt*1024 + (l15+16*l4)*16 + ks*4 + j
//   covering (q = qt*16+l15, k = kt*64+ks*16+l4*4+j)
__global__ __launch_bounds__(256) void maskpack_kernel(
    const int* node_types, const int* edge_types, const float* adjacency,
    u8* codes) {
  __shared__ uint lw[16 * 516 + 4];          // padded stride 516 (33KB)
  int blk = blockIdx.x;                       // 0..511
  int qt = blk & 127;
  int b = blk >> 7;
  int t = threadIdx.x;
  const int* ntb = node_types + b * Nn;
  const int* etb = edge_types + (size_t)b * Nn * Nn + (size_t)qt * 16 * Nn;
  const float* adjb = adjacency + (size_t)b * Nn * Nn + (size_t)qt * 16 * Nn;

  // Phase A: 8192 int4-triples, 32 per thread, contiguous across block
#pragma unroll 4
  for (int a = 0; a < 32; ++a) {
    int idx = a * 256 + t;                    // int4 index within (16 x 512)
    int row = idx >> 9;                       // 0..15
    int k4 = idx & 511;                       // int4 within row
    int k0 = k4 * 4;
    int ntq = ntb[qt * 16 + row];
    int4 et4 = *(const int4*)(etb + (size_t)row * Nn + k0);
    float4 a4 = *(const float4*)(adjb + (size_t)row * Nn + k0);
    int4 nt4 = *(const int4*)(ntb + k0);
    int e[4] = {et4.x, et4.y, et4.z, et4.w};
    int n[4] = {nt4.x, nt4.y, nt4.z, nt4.w};
    float av[4] = {a4.x, a4.y, a4.z, a4.w};
    uint word = 0;
#pragma unroll
    for (int j = 0; j < 4; ++j) {
      int code = e[j] + ((ntq == n[j]) ? 6 : 0) + ((av[j] != 0.0f) ? 12 : 0);
      word |= (uint)(code * 4) << (8 * j);
    }
    lw[row * 516 + k4] = word;
  }
  __syncthreads();

  // Phase B: write 8192 words as contiguous dwordx4 (16B/thread/iter)
  u8* rec = codes + (size_t)(b * 128 + qt) * 32768;
#pragma unroll
  for (int c = 0; c < 8; ++c) {
    int W = (c * 256 + t) * 4;                // output word base (dwordx4)
    int kt = W >> 8;
    int rem = W & 255;
    int l4 = rem >> 6;
    int l15 = (rem >> 2) & 15;
    int base = l15 * 516 + kt * 16 + l4;      // + 4*s for s=0..3 (ks)
    u32x4 o = {lw[base], lw[base + 4], lw[base + 8], lw[base + 12]};
    *(u32x4*)(rec + (size_t)W * 4) = o;
  }
}

// ================= QKV GEMM: [8192,256] @ [256,768] =================
// Q pre-scaled by 0.125*LOG2E (f32, before bf16 round); V written TRANSPOSED
// directly to Vtb[B,H,64,N].
__global__ __launch_bounds__(256) void qkv_kernel(const u16* xbf, const u16* wqkvT,
                                                  const float* bqkv,
                                                  u16* Qb, u16* Kb, u16* Vtb) {
  int cb = blockIdx.x;              // 0..11
  int rb = blockIdx.y;              // 0..127
  int w = threadIdx.x >> 6, lane = threadIdx.x & 63;
  int l15 = lane & 15, l4 = lane >> 4;
  int row0 = rb * 64 + w * 16;
  int col0 = cb * 64;
  const u16* xr = xbf + (size_t)(row0 + l15) * 256;
  f32x4 acc[4];
#pragma unroll
  for (int i = 0; i < 4; ++i) acc[i] = (f32x4){0.f, 0.f, 0.f, 0.f};
#pragma unroll
  for (int kst = 0; kst < 8; ++kst) {
    int k0 = kst * 32 + l4 * 8;
    bf16x8 a = ld8(xr + k0);
#pragma unroll
    for (int cs = 0; cs < 4; ++cs) {
      int col = col0 + cs * 16 + l15;
      bf16x8 bw = ld8(wqkvT + (size_t)col * 256 + k0);
      acc[cs] = MFMA16(a, bw, acc[cs]);
    }
  }
#pragma unroll
  for (int cs = 0; cs < 4; ++cs) {
    int col = col0 + cs * 16 + l15;
    float bias = bqkv[col];
    int which = col >> 8, c = col & 255;
    int h = c >> 6, hd = c & 63;
    float scale = (which == 0) ? SCLQ : 1.0f;
#pragma unroll
    for (int j = 0; j < 4; ++j) {
      int row = row0 + l4 * 4 + j;
      int bb = row >> 11, n = row & 2047;
      u16 val = f2bf((acc[cs][j] + bias) * scale);
      if (which == 2)
        Vtb[((size_t)((bb * Hh + h) * HD + hd)) * Nn + n] = val;
      else if (which == 0)
        Qb[(size_t)(((bb * Hh + h) * Nn + n)) * HD + hd] = val;
      else
        Kb[(size_t)(((bb * Hh + h) * Nn + n)) * HD + hd] = val;
    }
  }
}

// ================= attention: single-QK^T k-split (R12, best) =============
__global__ __launch_bounds__(256) void attn_kernel(
    const u16* Qb, const u16* Kb, const u16* Vtb, const u8* codes,
    const float* ee_g, float* attn_out, u16* ctx_ws) {
  __shared__ __align__(16) char kvb[4][2][8192];   // per-wave K(p1)/V(p2) dbuf
  __shared__ __align__(16) char pls[4][2048];      // per-wave P roundtrip
  __shared__ float lsh[4][16];

  int bid0 = blockIdx.x;
  int bid = ((bid0 & 7) << 8) | (bid0 >> 3);   // XCD-chunked (2048 % 8 == 0)
  int qt = bid & 127;
  int h = (bid >> 7) & 3;
  int b = bid >> 9;
  int w = threadIdx.x >> 6, lane = threadIdx.x & 63;
  int l15 = lane & 15, l4 = lane >> 4;
  int q0 = qt * 16;
  int bh = b * Hh + h;
  int wk0 = w * 512;                 // this wave's k-range start

  // 24-entry bias LUT (log2 domain, MSUB folded in), one value per lane 0..23
  float lutv = 0.f;
  {
    int ln = lane;
    int et = ln - 6 * (ln / 6);
    int tm = (ln / 6) & 1;
    int adj = ln / 12;
    if (ln < 24)
      lutv = (ee_g[et * Hh + h] + (tm ? 0.10f : -0.05f)) * LOG2E +
             (adj ? 0.f : -1.442695041e9f) - MSUB;
  }
  int lut_i = __float_as_int(lutv);

  // Q as B-fragment (pre-scaled by SCLQ in qkv_kernel)
  const u16* Qp = Qb + (size_t)(bh * Nn + q0 + l15) * HD;
  bf16x8 bq0 = ld8(Qp + l4 * 8);
  bf16x8 bq1 = ld8(Qp + 32 + l4 * 8);

  const char* Kgw = (const char*)(Kb + (size_t)bh * Nn * HD) + (size_t)wk0 * 128;
  const char* Vg = (const char*)(Vtb + (size_t)bh * HD * Nn);
  const u32x4* cp = (const u32x4*)codes + ((size_t)(b * 128 + qt) * 32) * 64;

  // staging: 8KB tile = 64 rows x 128B; LDS[o] = G[row*stride + swz(o)&127]
  int oS[8];
  const char* KgS[8];
  const char* VgS[8];
#pragma unroll
  for (int j = 0; j < 8; ++j) {
    int o = j * 1024 + lane * 16;
    oS[j] = o;
    int row = o >> 7;
    int sz = (o ^ ((row & 7) << 4)) & 127;
    KgS[j] = Kgw + (size_t)row * 128 + sz;                 // + kt*8192
    VgS[j] = Vg + (size_t)row * (Nn * 2) + wk0 * 2 + sz;   // + kt*128
  }
  char* myb0 = (char*)kvb[w][0];
  char* myb1 = (char*)kvb[w][1];

  int sw = (l15 & 7) << 4;
  int ra = (l15 * 128 + l4 * 16) ^ sw;
  char* pwave = (char*)pls[w];
  int pwbase = l15 * 128;

  uint p[8][8];                      // bf16x2 packed exp2 values (C-layout)
  float accl = 0.f;

  // ---------- pass 1: QK^T + bias + exp2, once ----------
#pragma unroll
  for (int j = 0; j < 8; ++j) stage16(KgS[j], myb0 + oS[j]);
  u32x4 cw = cp[(size_t)(w * 8) * 64 + lane];

#pragma unroll
  for (int i = 0; i < 8; ++i) {
    u32x4 cwn = cw;
    if (i < 7) {
      char* nb = (i & 1) ? myb0 : myb1;
#pragma unroll
      for (int j = 0; j < 8; ++j)
        stage16(KgS[j] + (size_t)(i + 1) * 8192, nb + oS[j]);
      cwn = cp[(size_t)(w * 8 + i + 1) * 64 + lane];
    }
    __builtin_amdgcn_sched_barrier(0);
    if (i < 7) asm volatile("s_waitcnt vmcnt(9) lgkmcnt(0)" ::: "memory");
    else       asm volatile("s_waitcnt vmcnt(0) lgkmcnt(0)" ::: "memory");
    __builtin_amdgcn_sched_barrier(0);
    const char* kcur = (i & 1) ? myb1 : myb0;
#pragma unroll
    for (int ks = 0; ks < 4; ++ks) {
      unsigned int cword = cw[ks];
      f32x4 acc;
#pragma unroll
      for (int j = 0; j < 4; ++j)
        acc[j] = __int_as_float(
            __builtin_amdgcn_ds_bpermute((cword >> (8 * j)) & 0xFF, lut_i));
      acc = MFMA16(ld8((const u16*)(kcur + ra + ks * 2048)), bq0, acc);
      acc = MFMA16(ld8((const u16*)(kcur + (ra ^ 64) + ks * 2048)), bq1, acc);
      float e0 = __builtin_amdgcn_exp2f(acc[0]);
      float e1 = __builtin_amdgcn_exp2f(acc[1]);
      float e2 = __builtin_amdgcn_exp2f(acc[2]);
      float e3 = __builtin_amdgcn_exp2f(acc[3]);
      accl += (e0 + e1) + (e2 + e3);
      asm("v_cvt_pk_bf16_f32 %0, %1, %2" : "=v"(p[i][ks * 2]) : "v"(e0), "v"(e1));
      asm("v_cvt_pk_bf16_f32 %0, %1, %2" : "=v"(p[i][ks * 2 + 1]) : "v"(e2), "v"(e3));
    }
    cw = cwn;
  }
  accl += __shfl_xor(accl, 16);
  accl += __shfl_xor(accl, 32);
  if (lane < 16) lsh[w][lane] = accl;
  __syncthreads();
  float tot = lsh[0][l15] + lsh[1][l15] + lsh[2][l15] + lsh[3][l15];
  bool zrow = (tot == 0.0f);
  float cscale = zrow ? (1.0f / 2048.0f) : (1.0f / tot);

  // ---------- pass 2: attn store + PV (no QK recompute) ----------
  f32x4 ctx[4];
#pragma unroll
  for (int i = 0; i < 4; ++i) ctx[i] = (f32x4){0.f, 0.f, 0.f, 0.f};
  float* attb = attn_out + (size_t)bh * Nn * Nn + (size_t)(q0 + l15) * Nn + wk0;

#pragma unroll
  for (int j = 0; j < 8; ++j) stage16(VgS[j], myb0 + oS[j]);

#pragma unroll
  for (int i = 0; i < 8; ++i) {
    if (i < 7) {
      char* nb = (i & 1) ? myb0 : myb1;
#pragma unroll
      for (int j = 0; j < 8; ++j)
        stage16(VgS[j] + (size_t)(i + 1) * 128, nb + oS[j]);
    }
    __builtin_amdgcn_sched_barrier(0);
    if (i == 0)     asm volatile("s_waitcnt vmcnt(8) lgkmcnt(0)" ::: "memory");
    else if (i < 7) asm volatile("s_waitcnt vmcnt(12) lgkmcnt(0)" ::: "memory");
    else            asm volatile("s_waitcnt vmcnt(4) lgkmcnt(0)" ::: "memory");
    __builtin_amdgcn_sched_barrier(0);
    const char* vcur = (i & 1) ? myb1 : myb0;

    uint pp[8];
#pragma unroll
    for (int r = 0; r < 8; ++r) pp[r] = zrow ? 0x3F803F80u : p[i][r];
    // P -> LDS (C-layout), for A-fragment re-read
#pragma unroll
    for (int ks = 0; ks < 4; ++ks) {
      int2 wv = {(int)pp[ks * 2], (int)pp[ks * 2 + 1]};
      *(int2*)(pwave + pwbase + ((ks * 32 + l4 * 8) ^ sw)) = wv;
    }
    // attn output: float(p)*cscale
#pragma unroll
    for (int ks = 0; ks < 4; ++ks) {
      uint u0 = pp[ks * 2], u1 = pp[ks * 2 + 1];
      f32x4 o;
      o[0] = __int_as_float((int)(u0 << 16)) * cscale;
      o[1] = __int_as_float((int)(u0 & 0xFFFF0000u)) * cscale;
      o[2] = __int_as_float((int)(u1 << 16)) * cscale;
      o[3] = __int_as_float((int)(u1 & 0xFFFF0000u)) * cscale;
      __builtin_nontemporal_store(o, (f32x4*)(attb + i * 64 + ks * 16 + l4 * 4));
    }
    // PV with unnormalized P
#pragma unroll
    for (int half = 0; half < 2; ++half) {
      bf16x8 pa = ld8((const u16*)(pwave + pwbase + ((half * 64 + l4 * 16) ^ sw)));
#pragma unroll
      for (int d = 0; d < 4; ++d) {
        bf16x8 v = ld8((const u16*)(vcur + d * 2048 + l15 * 128 +
                                    ((half * 64 + l4 * 16) ^ sw)));
        ctx[d] = MFMA16(pa, v, ctx[d]);
      }
    }
  }

  // per-row scale of partial ctx (rows = l4*4+j; cscale lives at lane==row)
  float csr[4];
#pragma unroll
  for (int j = 0; j < 4; ++j)
    csr[j] = __int_as_float(
        __builtin_amdgcn_ds_bpermute((l4 * 4 + j) * 4, __float_as_int(cscale)));
#pragma unroll
  for (int d = 0; d < 4; ++d)
#pragma unroll
    for (int j = 0; j < 4; ++j) ctx[d][j] *= csr[j];

  // combine partial ctx across the 4 k-split waves (reuse kvb as f32 scratch)
  __syncthreads();                       // all waves done with kvb as V
  float* creg = (float*)kvb;
  if (w > 0) {
    float* cs_ = creg + ((size_t)(w - 1) * 64 + lane) * 17;
#pragma unroll
    for (int d = 0; d < 4; ++d)
#pragma unroll
      for (int j = 0; j < 4; ++j) cs_[d * 4 + j] = ctx[d][j];
  }
  __syncthreads();
  if (w == 0) {
    float* c0 = creg + (size_t)lane * 17;
    float* c1 = creg + ((size_t)64 + lane) * 17;
    float* c2 = creg + ((size_t)128 + lane) * 17;
#pragma unroll
    for (int d = 0; d < 4; ++d) {
      int col = h * 64 + d * 16 + l15;
#pragma unroll
      for (int j = 0; j < 4; ++j) {
        float v = ctx[d][j] + c0[d * 4 + j] + c1[d * 4 + j] + c2[d * 4 + j];
        int qrow = q0 + l4 * 4 + j;
        ctx_ws[(size_t)(b * Nn + qrow) * Dd + col] = f2bf(v);
      }
    }
  }
}

// ================= out GEMM + residual + LayerNorm =================
__global__ __launch_bounds__(256) void outln_kernel(const u16* ctxb, const u16* woT,
                                                    const float* bo, const float* xf,
                                                    const float* ln_g, const float* ln_b,
                                                    float* yout) {
  __shared__ float ytile[32][257];
  __shared__ float muS[32], rvS[32];
  int bm0 = blockIdx.x * 32;
  int w = threadIdx.x >> 6, lane = threadIdx.x & 63;
  int l15 = lane & 15, l4 = lane >> 4;
  f32x4 acc[2][4];
#pragma unroll
  for (int q = 0; q < 2; ++q)
#pragma unroll
    for (int i = 0; i < 4; ++i) acc[q][i] = (f32x4){0.f, 0.f, 0.f, 0.f};
#pragma unroll
  for (int kst = 0; kst < 8; ++kst) {
    int k0 = kst * 32 + l4 * 8;
    bf16x8 a0 = ld8(ctxb + (size_t)(bm0 + l15) * 256 + k0);
    bf16x8 a1 = ld8(ctxb + (size_t)(bm0 + 16 + l15) * 256 + k0);
#pragma unroll
    for (int ds_ = 0; ds_ < 4; ++ds_) {
      bf16x8 bw = ld8(woT + (size_t)(w * 64 + ds_ * 16 + l15) * 256 + k0);
      acc[0][ds_] = MFMA16(a0, bw, acc[0][ds_]);
      acc[1][ds_] = MFMA16(a1, bw, acc[1][ds_]);
    }
  }
#pragma unroll
  for (int qs = 0; qs < 2; ++qs)
#pragma unroll
    for (int ds_ = 0; ds_ < 4; ++ds_) {
      int col = w * 64 + ds_ * 16 + l15;
      float bof = bo[col];
#pragma unroll
      for (int j = 0; j < 4; ++j) {
        int row = qs * 16 + l4 * 4 + j;
        ytile[row][col] = acc[qs][ds_][j] + bof + xf[(size_t)(bm0 + row) * 256 + col];
      }
    }
  __syncthreads();
  int row = threadIdx.x >> 3, seg = threadIdx.x & 7;
  float ps = 0.f, pq = 0.f;
#pragma unroll
  for (int c = 0; c < 32; ++c) {
    float v = ytile[row][seg * 32 + c];
    ps += v; pq += v * v;
  }
  ps += __shfl_xor(ps, 1); pq += __shfl_xor(pq, 1);
  ps += __shfl_xor(ps, 2); pq += __shfl_xor(pq, 2);
  ps += __shfl_xor(ps, 4); pq += __shfl_xor(pq, 4);
  if (seg == 0) {
    float mu = ps * (1.0f / 256.0f);
    muS[row] = mu;
    rvS[row] = rsqrtf(pq * (1.0f / 256.0f) - mu * mu + 1e-5f);
  }
  __syncthreads();
  float mu = muS[row], rv = rvS[row];
  float* yr = yout + (size_t)(bm0 + row) * 256;
#pragma unroll
  for (int c0 = 0; c0 < 32; c0 += 4) {
    int c = seg * 32 + c0;
    float4 o;
    o.x = (ytile[row][c + 0] - mu) * rv * ln_g[c + 0] + ln_b[c + 0];
    o.y = (ytile[row][c + 1] - mu) * rv * ln_g[c + 1] + ln_b[c + 1];
    o.z = (ytile[row][c + 2] - mu) * rv * ln_g[c + 2] + ln_b[c + 2];
    o.w = (ytile[row][c + 3] - mu) * rv * ln_g[c + 3] + ln_b[c + 3];
    *(float4*)(yr + c) = o;
  }
}

extern "C" void kernel_launch(void* const* d_in, const int* in_sizes, int n_in,
                              void* d_out, int out_size, void* d_ws, size_t ws_size,
                              hipStream_t stream) {
  const float* nodes = (const float*)d_in[0];
  const int* node_types = (const int*)d_in[1];
  const int* edge_types = (const int*)d_in[2];
  const float* adjacency = (const float*)d_in[3];
  const float* nte = (const float*)d_in[4];
  const float* ee = (const float*)d_in[5];
  const float* Wq = (const float*)d_in[6];
  const float* bq = (const float*)d_in[7];
  const float* Wk = (const float*)d_in[8];
  const float* bk = (const float*)d_in[9];
  const float* Wv = (const float*)d_in[10];
  const float* bv = (const float*)d_in[11];
  const float* Wo = (const float*)d_in[12];
  const float* bo = (const float*)d_in[13];
  const float* ln_g = (const float*)d_in[14];
  const float* ln_b = (const float*)d_in[15];

  float* y = (float*)d_out;
  float* attn = y + (size_t)Bsz * Nn * Dd;

  char* ws = (char*)d_ws;
  float* xf = (float*)(ws + OFF_X);
  u16* xbf = (u16*)(ws + OFF_XBF);
  u16* wqkvT = (u16*)(ws + OFF_WQKVT);
  u16* woT = (u16*)(ws + OFF_WOT);
  float* bqkv = (float*)(ws + OFF_BQKV);
  u16* Qb = (u16*)(ws + OFF_Q);
  u16* Kb = (u16*)(ws + OFF_K);
  u16* Vtb = (u16*)(ws + OFF_VT);
  u16* ctxb = (u16*)(ws + OFF_CTX);
  u8* codes = (u8*)(ws + OFF_CODES);

  pack_kernel<<<1027, 256, 0, stream>>>(Wq, Wk, Wv, Wo, bq, bk, bv, wqkvT, woT, bqkv);
  embed_kernel<<<2048, 256, 0, stream>>>(nodes, node_types, nte, xf, xbf);
  maskpack_kernel<<<512, 256, 0, stream>>>(node_types, edge_types, adjacency, codes);
  qkv_kernel<<<dim3(12, 128), 256, 0, stream>>>(xbf, wqkvT, bqkv, Qb, Kb, Vtb);
  attn_kernel<<<2048, 256, 0, stream>>>(Qb, Kb, Vtb, codes, ee, attn, ctxb);
  outln_kernel<<<256, 256, 0, stream>>>(ctxb, woT, bo, xf, ln_g, ln_b, y);
}

// Round 15
// 179.624 us; speedup vs baseline: 1.1287x; 1.0270x over previous
//
#include <hip/hip_runtime.h>

#define Bsz 4
#define Nn 2048
#define Dd 256
#define Hh 4
#define HD 64
#define NTt 5
#define ETt 6
#define LOG2E 1.4426950408889634f
#define MSUB 24.0f
#define SCLQ 0.18033688011112042f   // 0.125 * LOG2E, folded into Q at qkv time

typedef float f32x4 __attribute__((ext_vector_type(4)));
typedef __bf16 bf16x8 __attribute__((ext_vector_type(8)));
typedef unsigned int u32x4 __attribute__((ext_vector_type(4)));
typedef unsigned int u32x2 __attribute__((ext_vector_type(2)));
typedef unsigned short u16;
typedef unsigned char u8;
typedef unsigned int uint;

static __device__ __forceinline__ u16 f2bf(float f) {
  unsigned int u = __builtin_bit_cast(unsigned int, f);
  u = (u + 0x7fffu + ((u >> 16) & 1u)) >> 16;
  return (u16)u;
}

static __device__ __forceinline__ bf16x8 ld8(const u16* p) {
  return __builtin_bit_cast(bf16x8, *(const u32x4*)p);
}

// async global->LDS, 16B per lane; LDS dest = wave-uniform base + lane*16
static __device__ __forceinline__ void stage16(const void* g, void* l) {
  __builtin_amdgcn_global_load_lds(
      (const __attribute__((address_space(1))) uint*)g,
      (__attribute__((address_space(3))) uint*)l, 16, 0, 0);
}

#define MFMA16(a, b, c) __builtin_amdgcn_mfma_f32_16x16x32_bf16((a), (b), (c), 0, 0, 0)

// ---------------- ws layout (bytes) ----------------
#define OFF_X      0u            // f32  [8192][256]        8388608
#define OFF_XBF    8388608u      // bf16 [8192][256]        4194304
#define OFF_WQKVT  12582912u     // bf16 [768][256]         393216
#define OFF_WOT    12976128u     // bf16 [256][256]         131072
#define OFF_BQKV   13107200u     // f32  [768]              3072
#define OFF_Q      13110272u     // bf16 [B,H,N,64]         4194304
#define OFF_K      17304576u     // bf16 [B,H,N,64]         4194304
#define OFF_VT     25693184u     // bf16 [B,H,64,N]         4194304
#define OFF_CTX    29887488u     // bf16 [8192][256]        4194304
#define OFF_CODES  34081792u     // u8   [B,128,32,64,16]   16777216

// ================= pack weights (transposed, bf16) =================
__global__ void pack_kernel(const float* Wq, const float* Wk, const float* Wv,
                            const float* Wo, const float* bq, const float* bk,
                            const float* bv, u16* wqkvT, u16* woT, float* bqkv) {
  int tid = blockIdx.x * 256 + threadIdx.x;
  if (tid < 196608) {                 // WqkvT[c][k] = W_which[k][cc]
    int c = tid >> 8, k = tid & 255;
    int which = c >> 8, cc = c & 255;
    const float* W = (which == 0) ? Wq : ((which == 1) ? Wk : Wv);
    wqkvT[tid] = f2bf(W[k * 256 + cc]);
  } else if (tid < 262144) {          // WoT[c][k] = Wo[k][c]
    int t2 = tid - 196608;
    int c = t2 >> 8, k = t2 & 255;
    woT[t2] = f2bf(Wo[k * 256 + c]);
  } else if (tid < 262912) {
    int c = tid - 262144;
    int which = c >> 8, cc = c & 255;
    bqkv[c] = (which == 0) ? bq[cc] : ((which == 1) ? bk[cc] : bv[cc]);
  }
}

// ================= x = nodes + node_type_embed[nt] =================
__global__ void embed_kernel(const float* nodes, const int* node_types,
                             const float* nte, float* xf, u16* xbf) {
  int t = blockIdx.x * 256 + threadIdx.x;    // 524288 threads, 4 floats each
  int flat = t * 4;
  int bn = flat >> 8, d0 = flat & 255;
  int nt = node_types[bn];
  float4 nv = *(const float4*)(nodes + flat);
  float4 ev = *(const float4*)(nte + nt * 256 + d0);
  float4 x4;
  x4.x = nv.x + ev.x; x4.y = nv.y + ev.y; x4.z = nv.z + ev.z; x4.w = nv.w + ev.w;
  *(float4*)(xf + flat) = x4;
  ushort4 xb;
  xb.x = f2bf(x4.x); xb.y = f2bf(x4.y); xb.z = f2bf(x4.z); xb.w = f2bf(x4.w);
  *(ushort4*)(xbf + flat) = xb;
}

// ================= mask pack v2: LDS-transposed, coalesced R/W ============
__global__ __launch_bounds__(256) void maskpack_kernel(
    const int* node_types, const int* edge_types, const float* adjacency,
    u8* codes) {
  __shared__ uint lw[16 * 516 + 4];          // padded stride 516 (33KB)
  int blk = blockIdx.x;                       // 0..511
  int qt = blk & 127;
  int b = blk >> 7;
  int t = threadIdx.x;
  const int* ntb = node_types + b * Nn;
  const int* etb = edge_types + (size_t)b * Nn * Nn + (size_t)qt * 16 * Nn;
  const float* adjb = adjacency + (size_t)b * Nn * Nn + (size_t)qt * 16 * Nn;

#pragma unroll 4
  for (int a = 0; a < 32; ++a) {
    int idx = a * 256 + t;                    // int4 index within (16 x 512)
    int row = idx >> 9;                       // 0..15
    int k4 = idx & 511;                       // int4 within row
    int k0 = k4 * 4;
    int ntq = ntb[qt * 16 + row];
    int4 et4 = *(const int4*)(etb + (size_t)row * Nn + k0);
    float4 a4 = *(const float4*)(adjb + (size_t)row * Nn + k0);
    int4 nt4 = *(const int4*)(ntb + k0);
    int e[4] = {et4.x, et4.y, et4.z, et4.w};
    int n[4] = {nt4.x, nt4.y, nt4.z, nt4.w};
    float av[4] = {a4.x, a4.y, a4.z, a4.w};
    uint word = 0;
#pragma unroll
    for (int j = 0; j < 4; ++j) {
      int code = e[j] + ((ntq == n[j]) ? 6 : 0) + ((av[j] != 0.0f) ? 12 : 0);
      word |= (uint)(code * 4) << (8 * j);
    }
    lw[row * 516 + k4] = word;
  }
  __syncthreads();

  u8* rec = codes + (size_t)(b * 128 + qt) * 32768;
#pragma unroll
  for (int c = 0; c < 8; ++c) {
    int W = (c * 256 + t) * 4;                // output word base (dwordx4)
    int kt = W >> 8;
    int rem = W & 255;
    int l4 = rem >> 6;
    int l15 = (rem >> 2) & 15;
    int base = l15 * 516 + kt * 16 + l4;      // + 4*s for s=0..3 (ks)
    u32x4 o = {lw[base], lw[base + 4], lw[base + 8], lw[base + 12]};
    *(u32x4*)(rec + (size_t)W * 4) = o;
  }
}

// ================= QKV GEMM: [8192,256] @ [256,768] =================
__global__ __launch_bounds__(256) void qkv_kernel(const u16* xbf, const u16* wqkvT,
                                                  const float* bqkv,
                                                  u16* Qb, u16* Kb, u16* Vtb) {
  int cb = blockIdx.x;              // 0..11
  int rb = blockIdx.y;              // 0..127
  int w = threadIdx.x >> 6, lane = threadIdx.x & 63;
  int l15 = lane & 15, l4 = lane >> 4;
  int row0 = rb * 64 + w * 16;
  int col0 = cb * 64;
  const u16* xr = xbf + (size_t)(row0 + l15) * 256;
  f32x4 acc[4];
#pragma unroll
  for (int i = 0; i < 4; ++i) acc[i] = (f32x4){0.f, 0.f, 0.f, 0.f};
#pragma unroll
  for (int kst = 0; kst < 8; ++kst) {
    int k0 = kst * 32 + l4 * 8;
    bf16x8 a = ld8(xr + k0);
#pragma unroll
    for (int cs = 0; cs < 4; ++cs) {
      int col = col0 + cs * 16 + l15;
      bf16x8 bw = ld8(wqkvT + (size_t)col * 256 + k0);
      acc[cs] = MFMA16(a, bw, acc[cs]);
    }
  }
#pragma unroll
  for (int cs = 0; cs < 4; ++cs) {
    int col = col0 + cs * 16 + l15;
    float bias = bqkv[col];
    int which = col >> 8, c = col & 255;
    int h = c >> 6, hd = c & 63;
    float scale = (which == 0) ? SCLQ : 1.0f;
#pragma unroll
    for (int j = 0; j < 4; ++j) {
      int row = row0 + l4 * 4 + j;
      int bb = row >> 11, n = row & 2047;
      u16 val = f2bf((acc[cs][j] + bias) * scale);
      if (which == 2)
        Vtb[((size_t)((bb * Hh + h) * HD + hd)) * Nn + n] = val;
      else if (which == 0)
        Qb[(size_t)(((bb * Hh + h) * Nn + n)) * HD + hd] = val;
      else
        Kb[(size_t)(((bb * Hh + h) * Nn + n)) * HD + hd] = val;
    }
  }
}

// ================= attention: 8-wave k-split, 32-col tiles =================
// block = (b, h, 16-row q-tile): 2048 blocks x 8 waves (512 thr); wave w owns
// k in [w*256, w*256+256) = 8 iterations of 32 cols. Single QK^T (p[8][4]
// packed bf16 regs), unnormalized PV, counted vmcnt, zero loop barriers.
// LDS exactly 80KB -> 2 blocks/CU; VGPR pinned <=128 -> 16 waves/CU.
__global__ __launch_bounds__(512, 4) void attn_kernel(
    const u16* Qb, const u16* Kb, const u16* Vtb, const u8* codes,
    const float* ee_g, float* attn_out, u16* ctx_ws) {
  __shared__ __align__(16) char smem[81920];
  // [0,65536): per-wave K/V dbuf (wave w: smem + w*8192, two 4KB buffers)
  // [65536,81920): per-wave P (2KB); first 512B also alias lsh (barrier-fenced)

  int bid0 = blockIdx.x;
  int bid = ((bid0 & 7) << 8) | (bid0 >> 3);   // XCD-chunked (2048 % 8 == 0)
  int qt = bid & 127;
  int h = (bid >> 7) & 3;
  int b = bid >> 9;
  int w = threadIdx.x >> 6, lane = threadIdx.x & 63;
  int l15 = lane & 15, l4 = lane >> 4;
  int q0 = qt * 16;
  int bh = b * Hh + h;
  int wk0 = w * 256;                 // this wave's k-range start

  float* lsh = (float*)(smem + 65536);
  char* pwave = smem + 65536 + w * 2048;
  char* kv0 = smem + w * 8192;
  char* kv1 = kv0 + 4096;

  // 24-entry bias LUT (log2 domain, MSUB folded in), one value per lane 0..23
  float lutv = 0.f;
  {
    int ln = lane;
    int et = ln - 6 * (ln / 6);
    int tm = (ln / 6) & 1;
    int adj = ln / 12;
    if (ln < 24)
      lutv = (ee_g[et * Hh + h] + (tm ? 0.10f : -0.05f)) * LOG2E +
             (adj ? 0.f : -1.442695041e9f) - MSUB;
  }
  int lut_i = __float_as_int(lutv);

  // Q as B-fragment (pre-scaled by SCLQ in qkv_kernel)
  const u16* Qp = Qb + (size_t)(bh * Nn + q0 + l15) * HD;
  bf16x8 bq0 = ld8(Qp + l4 * 8);
  bf16x8 bq1 = ld8(Qp + 32 + l4 * 8);

  // K staging (4KB tile = 32 n-rows x 128B): dest slot j*64+lane holds
  // global row j*8+(lane>>3), swizzled col ((lane&7)*16)^(((lane>>3)&7)<<4)
  const char* Kg = (const char*)Kb + (size_t)bh * Nn * 128 + (size_t)wk0 * 128;
  const char* KgS[4];
  {
    int colK = ((lane & 7) * 16) ^ (((lane >> 3) & 7) << 4);
#pragma unroll
    for (int j = 0; j < 4; ++j)
      KgS[j] = Kg + (size_t)(j * 8 + (lane >> 3)) * 128 + colK;
  }
  // V staging (4KB tile = 64 d-rows x 64B): dest slot j*64+lane holds
  // global (r = j*16+(lane>>2), s = (lane&3)^(lane>>4)); LDS layout
  // f(r,s) = (r&15)*4 + (s ^ ((r>>2)&3)) + (r>>4)*64   [16B slots]
  const char* Vg = (const char*)Vtb + (size_t)bh * HD * Nn * 2 + (size_t)wk0 * 2;
  const char* VgS[4];
  {
    int sV = (((lane & 3) ^ (lane >> 4)) & 3) * 16;
#pragma unroll
    for (int j = 0; j < 4; ++j)
      VgS[j] = Vg + (size_t)(j * 16 + (lane >> 2)) * (Nn * 2) + sV;
  }

  // codes: iteration i -> kt = w*4 + (i>>1), half = i&1 (8B dwordx2)
  const char* cpb = (const char*)codes + (size_t)(b * 128 + qt) * 32768 +
                    (size_t)(w * 4) * 1024 + lane * 16;

  int swK = (l15 & 7) << 4;
  int raK = (l15 * 128 + l4 * 16) ^ swK;              // + ks*2048; ^64 hd-hi
  int rv = l15 * 64 + ((l4 ^ ((l15 >> 2) & 3)) * 16); // P/V fragment read

  uint p[8][4];                      // bf16x2 packed exp2 values
  float accl = 0.f;

  // ---------- pass 1: QK^T + bias + exp2, once ----------
  u32x2 cw = *(const u32x2*)cpb;
#pragma unroll
  for (int j = 0; j < 4; ++j) stage16(KgS[j], kv0 + j * 1024);
  // FIFO tail: [cw(1), K0(4)] = 5

#pragma unroll
  for (int i = 0; i < 8; ++i) {
    u32x2 cwn = cw;
    char* kcur = (i & 1) ? kv1 : kv0;
    char* knxt = (i & 1) ? kv0 : kv1;
    if (i < 7) {
      cwn = *(const u32x2*)(cpb + ((i + 1) >> 1) * 1024 + ((i + 1) & 1) * 8);
#pragma unroll
      for (int j = 0; j < 4; ++j)
        stage16(KgS[j] + (size_t)(i + 1) * 4096, knxt + j * 1024);
    }
    __builtin_amdgcn_sched_barrier(0);
    if (i < 7) asm volatile("s_waitcnt vmcnt(5) lgkmcnt(0)" ::: "memory");
    else       asm volatile("s_waitcnt vmcnt(0) lgkmcnt(0)" ::: "memory");
    __builtin_amdgcn_sched_barrier(0);
#pragma unroll
    for (int ks = 0; ks < 2; ++ks) {
      uint cword = cw[ks];
      f32x4 acc;
#pragma unroll
      for (int j = 0; j < 4; ++j)
        acc[j] = __int_as_float(
            __builtin_amdgcn_ds_bpermute((int)((cword >> (8 * j)) & 0xFFu), lut_i));
      acc = MFMA16(ld8((const u16*)(kcur + raK + ks * 2048)), bq0, acc);
      acc = MFMA16(ld8((const u16*)(kcur + (raK ^ 64) + ks * 2048)), bq1, acc);
      float e0 = __builtin_amdgcn_exp2f(acc[0]);
      float e1 = __builtin_amdgcn_exp2f(acc[1]);
      float e2 = __builtin_amdgcn_exp2f(acc[2]);
      float e3 = __builtin_amdgcn_exp2f(acc[3]);
      accl += (e0 + e1) + (e2 + e3);
      asm("v_cvt_pk_bf16_f32 %0, %1, %2" : "=v"(p[i][ks * 2]) : "v"(e0), "v"(e1));
      asm("v_cvt_pk_bf16_f32 %0, %1, %2" : "=v"(p[i][ks * 2 + 1]) : "v"(e2), "v"(e3));
    }
    cw = cwn;
  }
  accl += __shfl_xor(accl, 16);
  accl += __shfl_xor(accl, 32);
  if (lane < 16) lsh[w * 16 + lane] = accl;
  __syncthreads();
  float tot = 0.f;
#pragma unroll
  for (int ww = 0; ww < 8; ++ww) tot += lsh[ww * 16 + l15];
  bool zrow = (tot == 0.0f);
  float cscale = zrow ? (1.0f / 2048.0f) : (1.0f / tot);
  __syncthreads();   // lsh read done before P writes overwrite its region

  // ---------- pass 2: attn store + PV (no QK recompute) ----------
  f32x4 ctx[4];
#pragma unroll
  for (int i = 0; i < 4; ++i) ctx[i] = (f32x4){0.f, 0.f, 0.f, 0.f};
  float* attb = attn_out + (size_t)bh * Nn * Nn + (size_t)(q0 + l15) * Nn + wk0;

#pragma unroll
  for (int j = 0; j < 4; ++j) stage16(VgS[j], kv0 + j * 1024);

#pragma unroll
  for (int i = 0; i < 8; ++i) {
    char* vcur = (i & 1) ? kv1 : kv0;
    char* vnxt = (i & 1) ? kv0 : kv1;
    if (i < 7) {
#pragma unroll
      for (int j = 0; j < 4; ++j)
        stage16(VgS[j] + (size_t)(i + 1) * 64, vnxt + j * 1024);
    }
    __builtin_amdgcn_sched_barrier(0);
    if (i == 0)     asm volatile("s_waitcnt vmcnt(4) lgkmcnt(0)" ::: "memory");
    else if (i < 7) asm volatile("s_waitcnt vmcnt(6) lgkmcnt(0)" ::: "memory");
    else            asm volatile("s_waitcnt vmcnt(2) lgkmcnt(0)" ::: "memory");
    __builtin_amdgcn_sched_barrier(0);

    uint pp[4];
#pragma unroll
    for (int r = 0; r < 4; ++r) pp[r] = zrow ? 0x3F803F80u : p[i][r];
    // P -> LDS (swizzled 64B rows)
#pragma unroll
    for (int ks = 0; ks < 2; ++ks) {
      int slot = (ks * 2 + (l4 >> 1)) ^ ((l15 >> 2) & 3);
      int2 wv = {(int)pp[ks * 2], (int)pp[ks * 2 + 1]};
      *(int2*)(pwave + l15 * 64 + slot * 16 + (l4 & 1) * 8) = wv;
    }
    // attn output: float(p)*cscale
#pragma unroll
    for (int ks = 0; ks < 2; ++ks) {
      uint u0 = pp[ks * 2], u1 = pp[ks * 2 + 1];
      f32x4 o;
      o[0] = __int_as_float((int)(u0 << 16)) * cscale;
      o[1] = __int_as_float((int)(u0 & 0xFFFF0000u)) * cscale;
      o[2] = __int_as_float((int)(u1 << 16)) * cscale;
      o[3] = __int_as_float((int)(u1 & 0xFFFF0000u)) * cscale;
      __builtin_nontemporal_store(o, (f32x4*)(attb + i * 32 + ks * 16 + l4 * 4));
    }
    // PV with unnormalized P
    bf16x8 pa = ld8((const u16*)(pwave + rv));
#pragma unroll
    for (int d = 0; d < 4; ++d) {
      bf16x8 v = ld8((const u16*)(vcur + d * 1024 + rv));
      ctx[d] = MFMA16(pa, v, ctx[d]);
    }
  }

  // per-row scale of partial ctx (rows = l4*4+j; cscale lives at lane==row)
  float csr[4];
#pragma unroll
  for (int j = 0; j < 4; ++j)
    csr[j] = __int_as_float(
        __builtin_amdgcn_ds_bpermute((l4 * 4 + j) * 4, __float_as_int(cscale)));
#pragma unroll
  for (int d = 0; d < 4; ++d)
#pragma unroll
    for (int j = 0; j < 4; ++j) ctx[d][j] *= csr[j];

  // combine partial ctx across the 8 k-split waves (reuse K/V region)
  __syncthreads();
  float* creg = (float*)smem;
  if (w > 0) {
    float* cs_ = creg + ((size_t)(w - 1) * 64 + lane) * 17;
#pragma unroll
    for (int d = 0; d < 4; ++d)
#pragma unroll
      for (int j = 0; j < 4; ++j) cs_[d * 4 + j] = ctx[d][j];
  }
  __syncthreads();
  if (w == 0) {
#pragma unroll
    for (int d = 0; d < 4; ++d) {
      int col = h * 64 + d * 16 + l15;
#pragma unroll
      for (int j = 0; j < 4; ++j) {
        float v = ctx[d][j];
#pragma unroll
        for (int ww = 0; ww < 7; ++ww)
          v += creg[((size_t)ww * 64 + lane) * 17 + d * 4 + j];
        int qrow = q0 + l4 * 4 + j;
        ctx_ws[(size_t)(b * Nn + qrow) * Dd + col] = f2bf(v);
      }
    }
  }
}

// ================= out GEMM + residual + LayerNorm =================
__global__ __launch_bounds__(256) void outln_kernel(const u16* ctxb, const u16* woT,
                                                    const float* bo, const float* xf,
                                                    const float* ln_g, const float* ln_b,
                                                    float* yout) {
  __shared__ float ytile[32][257];
  __shared__ float muS[32], rvS[32];
  int bm0 = blockIdx.x * 32;
  int w = threadIdx.x >> 6, lane = threadIdx.x & 63;
  int l15 = lane & 15, l4 = lane >> 4;
  f32x4 acc[2][4];
#pragma unroll
  for (int q = 0; q < 2; ++q)
#pragma unroll
    for (int i = 0; i < 4; ++i) acc[q][i] = (f32x4){0.f, 0.f, 0.f, 0.f};
#pragma unroll
  for (int kst = 0; kst < 8; ++kst) {
    int k0 = kst * 32 + l4 * 8;
    bf16x8 a0 = ld8(ctxb + (size_t)(bm0 + l15) * 256 + k0);
    bf16x8 a1 = ld8(ctxb + (size_t)(bm0 + 16 + l15) * 256 + k0);
#pragma unroll
    for (int ds_ = 0; ds_ < 4; ++ds_) {
      bf16x8 bw = ld8(woT + (size_t)(w * 64 + ds_ * 16 + l15) * 256 + k0);
      acc[0][ds_] = MFMA16(a0, bw, acc[0][ds_]);
      acc[1][ds_] = MFMA16(a1, bw, acc[1][ds_]);
    }
  }
#pragma unroll
  for (int qs = 0; qs < 2; ++qs)
#pragma unroll
    for (int ds_ = 0; ds_ < 4; ++ds_) {
      int col = w * 64 + ds_ * 16 + l15;
      float bof = bo[col];
#pragma unroll
      for (int j = 0; j < 4; ++j) {
        int row = qs * 16 + l4 * 4 + j;
        ytile[row][col] = acc[qs][ds_][j] + bof + xf[(size_t)(bm0 + row) * 256 + col];
      }
    }
  __syncthreads();
  int row = threadIdx.x >> 3, seg = threadIdx.x & 7;
  float ps = 0.f, pq = 0.f;
#pragma unroll
  for (int c = 0; c < 32; ++c) {
    float v = ytile[row][seg * 32 + c];
    ps += v; pq += v * v;
  }
  ps += __shfl_xor(ps, 1); pq += __shfl_xor(pq, 1);
  ps += __shfl_xor(ps, 2); pq += __shfl_xor(pq, 2);
  ps += __shfl_xor(ps, 4); pq += __shfl_xor(pq, 4);
  if (seg == 0) {
    float mu = ps * (1.0f / 256.0f);
    muS[row] = mu;
    rvS[row] = rsqrtf(pq * (1.0f / 256.0f) - mu * mu + 1e-5f);
  }
  __syncthreads();
  float mu = muS[row], rv = rvS[row];
  float* yr = yout + (size_t)(bm0 + row) * 256;
#pragma unroll
  for (int c0 = 0; c0 < 32; c0 += 4) {
    int c = seg * 32 + c0;
    float4 o;
    o.x = (ytile[row][c + 0] - mu) * rv * ln_g[c + 0] + ln_b[c + 0];
    o.y = (ytile[row][c + 1] - mu) * rv * ln_g[c + 1] + ln_b[c + 1];
    o.z = (ytile[row][c + 2] - mu) * rv * ln_g[c + 2] + ln_b[c + 2];
    o.w = (ytile[row][c + 3] - mu) * rv * ln_g[c + 3] + ln_b[c + 3];
    *(float4*)(yr + c) = o;
  }
}

extern "C" void kernel_launch(void* const* d_in, const int* in_sizes, int n_in,
                              void* d_out, int out_size, void* d_ws, size_t ws_size,
                              hipStream_t stream) {
  const float* nodes = (const float*)d_in[0];
  const int* node_types = (const int*)d_in[1];
  const int* edge_types = (const int*)d_in[2];
  const float* adjacency = (const float*)d_in[3];
  const float* nte = (const float*)d_in[4];
  const float* ee = (const float*)d_in[5];
  const float* Wq = (const float*)d_in[6];
  const float* bq = (const float*)d_in[7];
  const float* Wk = (const float*)d_in[8];
  const float* bk = (const float*)d_in[9];
  const float* Wv = (const float*)d_in[10];
  const float* bv = (const float*)d_in[11];
  const float* Wo = (const float*)d_in[12];
  const float* bo = (const float*)d_in[13];
  const float* ln_g = (const float*)d_in[14];
  const float* ln_b = (const float*)d_in[15];

  float* y = (float*)d_out;
  float* attn = y + (size_t)Bsz * Nn * Dd;

  char* ws = (char*)d_ws;
  float* xf = (float*)(ws + OFF_X);
  u16* xbf = (u16*)(ws + OFF_XBF);
  u16* wqkvT = (u16*)(ws + OFF_WQKVT);
  u16* woT = (u16*)(ws + OFF_WOT);
  float* bqkv = (float*)(ws + OFF_BQKV);
  u16* Qb = (u16*)(ws + OFF_Q);
  u16* Kb = (u16*)(ws + OFF_K);
  u16* Vtb = (u16*)(ws + OFF_VT);
  u16* ctxb = (u16*)(ws + OFF_CTX);
  u8* codes = (u8*)(ws + OFF_CODES);

  pack_kernel<<<1027, 256, 0, stream>>>(Wq, Wk, Wv, Wo, bq, bk, bv, wqkvT, woT, bqkv);
  embed_kernel<<<2048, 256, 0, stream>>>(nodes, node_types, nte, xf, xbf);
  maskpack_kernel<<<512, 256, 0, stream>>>(node_types, edge_types, adjacency, codes);
  qkv_kernel<<<dim3(12, 128), 256, 0, stream>>>(xbf, wqkvT, bqkv, Qb, Kb, Vtb);
  attn_kernel<<<2048, 512, 0, stream>>>(Qb, Kb, Vtb, codes, ee, attn, ctxb);
  outln_kernel<<<256, 256, 0, stream>>>(ctxb, woT, bo, xf, ln_g, ln_b, y);
}